// Round 3
// baseline (150.124 us; speedup 1.0000x reference)
//
#include <hip/hip_runtime.h>

typedef _Float16 half8 __attribute__((ext_vector_type(8)));
typedef _Float16 half4_t __attribute__((ext_vector_type(4)));
typedef float floatx4 __attribute__((ext_vector_type(4)));

#define LP 136  // LDS row pitch in halves: 272B rows, 16B-aligned, 4-bank stride for b128

// Prep: blocks [0,96) repack W1/W2 to MFMA A-frag order (fp16),
// blocks [96,..) convert x to fp16 (xh = L2-resident 6.4 MB copy).
__global__ __launch_bounds__(256) void prep_kernel(
    const float* __restrict__ x,
    const float* __restrict__ W1, const float* __restrict__ W2,
    _Float16* __restrict__ wsh, _Float16* __restrict__ xh, int n_x8)
{
    int b = blockIdx.x;
    if (b < 96) {
        int tid = b * 256 + threadIdx.x;
        if (tid < 16384) {                    // W1 cols 1..128: 8 mtiles x 4 kb x 512
            int c = tid >> 9, r = tid & 511;
            int L = r >> 3, jj = r & 7;
            int mt = c >> 2, kb = c & 3;
            int n = mt * 16 + (L & 15);
            int k = kb * 32 + (L >> 4) * 8 + jj;
            wsh[tid] = (_Float16)W1[n * 129 + 1 + k];
        } else {                              // W2: 4 mtiles x 4 kb x 512
            int t = tid - 16384;
            int c = t >> 9, r = t & 511;
            int L = r >> 3, jj = r & 7;
            int mt = c >> 2, kb = c & 3;
            int i = mt * 16 + (L & 15);
            int j = kb * 32 + (L >> 4) * 8 + jj;
            wsh[tid] = (_Float16)W2[i * 128 + j];
        }
    } else {
        int t2 = (b - 96) * 256 + threadIdx.x;
        if (t2 < n_x8) {
            const float4* p = (const float4*)(x + (size_t)t2 * 8);
            float4 v0 = p[0], v1 = p[1];
            half8 h = {(_Float16)v0.x, (_Float16)v0.y, (_Float16)v0.z, (_Float16)v0.w,
                       (_Float16)v1.x, (_Float16)v1.y, (_Float16)v1.z, (_Float16)v1.w};
            *(half8*)(xh + (size_t)t2 * 8) = h;
        }
    }
}

// e-sliced: wave w owns edges [blk*128 + 32w, +32). All LDS traffic wave-local
// except the parameter arrays (one barrier). h1 aliases hA rows of own edges.
__global__ __launch_bounds__(256, 4) void edge_mlp_kernel(
    const _Float16* __restrict__ xh,
    const int* __restrict__ ei,
    const float* __restrict__ ew,
    const float* __restrict__ W1, const float* __restrict__ b1,
    const float* __restrict__ b2,
    const float* __restrict__ W3, const float* __restrict__ b3,
    const _Float16* __restrict__ wf,
    float* __restrict__ out, int E)
{
    __shared__ __align__(16) _Float16 hA[128 * LP];
    __shared__ float s_b1[128];
    __shared__ float s_c0[128];   // W1[:,0] (edge-weight column, rank-1 epilogue)
    __shared__ float s_b2[64];
    __shared__ float s_w3[64];

    const int tid = threadIdx.x;
    const int e_blk = blockIdx.x * 128;
    const int lane = tid & 63;
    const int wave = tid >> 6;
    const int lrow = lane & 15;
    const int quad = lane >> 4;

    if (tid < 128) {
        s_b1[tid] = b1[tid];
        s_c0[tid] = W1[tid * 129];
    } else if (tid < 192) {
        int i = tid - 128;
        s_b2[i] = b2[i];
        s_w3[i] = W3[i];
    }

    // ---- wave-local gather: lane pair (2 lanes/edge) copies one node row ----
    {
        int e_loc = wave * 32 + (lane >> 1);
        int part = lane & 1;                  // 0 = src half (k 0..63), 1 = tgt
        int e = e_blk + e_loc; if (e >= E) e = E - 1;
        int node = ei[(size_t)part * E + e];
        const _Float16* rp = xh + (size_t)node * 64;
        _Float16* dst = &hA[e_loc * LP + part * 64];
#pragma unroll
        for (int q = 0; q < 8; ++q)
            *(half8*)(dst + q * 8) = *(const half8*)(rp + q * 8);
    }
    __syncthreads();   // params visible to all waves (gather is wave-local)

    // per-lane edge weights for the rank-1 epilogue
    float ewv[2];
#pragma unroll
    for (int et = 0; et < 2; ++et) {
        int e = e_blk + wave * 32 + et * 16 + lrow;
        if (e >= E) e = E - 1;
        ewv[et] = ew[e];
    }

    // ---- layer 1: for wave's 32 edges, all 128 outputs ----
    half8 bfr[2][4];
#pragma unroll
    for (int et = 0; et < 2; ++et)
#pragma unroll
        for (int kb = 0; kb < 4; ++kb)
            bfr[et][kb] = *(const half8*)(&hA[(wave * 32 + et * 16 + lrow) * LP + kb * 32 + quad * 8]);

#pragma unroll
    for (int mt = 0; mt < 8; ++mt) {
        half8 afr[4];
#pragma unroll
        for (int kb = 0; kb < 4; ++kb)
            afr[kb] = *(const half8*)(wf + (mt * 4 + kb) * 512 + lane * 8);
        floatx4 bb = *(const floatx4*)(&s_b1[mt * 16 + quad * 4]);
        floatx4 cc = *(const floatx4*)(&s_c0[mt * 16 + quad * 4]);
#pragma unroll
        for (int et = 0; et < 2; ++et) {
            floatx4 a = {0.f, 0.f, 0.f, 0.f};
#pragma unroll
            for (int kb = 0; kb < 4; ++kb)
                a = __builtin_amdgcn_mfma_f32_16x16x32_f16(afr[kb], bfr[et][kb], a, 0, 0, 0);
            half4_t hv;
#pragma unroll
            for (int r = 0; r < 4; ++r)
                hv[r] = (_Float16)fmaxf(a[r] + bb[r] + ewv[et] * cc[r], 0.f);
            // h1[e][n] into the wave's own hA rows (in-order DS pipe: reads above done)
            *(half4_t*)(&hA[(wave * 32 + et * 16 + lrow) * LP + mt * 16 + quad * 4]) = hv;
        }
    }

    // ---- layer 2 (+fused layer 3): wave-local h1 read, no barrier ----
    half8 b2fr[2][4];
#pragma unroll
    for (int et = 0; et < 2; ++et)
#pragma unroll
        for (int kb = 0; kb < 4; ++kb)
            b2fr[et][kb] = *(const half8*)(&hA[(wave * 32 + et * 16 + lrow) * LP + kb * 32 + quad * 8]);

    float p[2] = {0.f, 0.f};
#pragma unroll
    for (int mt = 0; mt < 4; ++mt) {
        half8 afr[4];
#pragma unroll
        for (int kb = 0; kb < 4; ++kb)
            afr[kb] = *(const half8*)(wf + 16384 + (mt * 4 + kb) * 512 + lane * 8);
        floatx4 bb = *(const floatx4*)(&s_b2[mt * 16 + quad * 4]);
        floatx4 ww = *(const floatx4*)(&s_w3[mt * 16 + quad * 4]);
#pragma unroll
        for (int et = 0; et < 2; ++et) {
            floatx4 a = {0.f, 0.f, 0.f, 0.f};
#pragma unroll
            for (int kb = 0; kb < 4; ++kb)
                a = __builtin_amdgcn_mfma_f32_16x16x32_f16(afr[kb], b2fr[et][kb], a, 0, 0, 0);
#pragma unroll
            for (int r = 0; r < 4; ++r)
                p[et] += fmaxf(a[r] + bb[r], 0.f) * ww[r];
        }
    }
#pragma unroll
    for (int et = 0; et < 2; ++et) {
        p[et] += __shfl_xor(p[et], 16, 64);
        p[et] += __shfl_xor(p[et], 32, 64);
    }
    float b3v = b3[0];
    if (quad < 2) {
        int oe = e_blk + wave * 32 + quad * 16 + lrow;
        if (oe < E) out[oe] = b3v + p[quad];
    }
}

extern "C" void kernel_launch(void* const* d_in, const int* in_sizes, int n_in,
                              void* d_out, int out_size, void* d_ws, size_t ws_size,
                              hipStream_t stream) {
    const float* x  = (const float*)d_in[0];
    const int*   ei = (const int*)d_in[1];   // int32 (verified round 1)
    const float* ew = (const float*)d_in[2];
    const float* W1 = (const float*)d_in[3];
    const float* b1 = (const float*)d_in[4];
    const float* W2 = (const float*)d_in[5];
    const float* b2 = (const float*)d_in[6];
    const float* W3 = (const float*)d_in[7];
    const float* b3 = (const float*)d_in[8];
    float* out = (float*)d_out;
    const int E = in_sizes[2];               // n_edges
    const int n_x = in_sizes[0];
    const int n_x8 = n_x / 8;

    _Float16* wsh = (_Float16*)d_ws;                  // 24576 halves = 48 KiB
    _Float16* xh  = (_Float16*)((char*)d_ws + 49152); // fp16 x copy, 6.4 MB

    int xblk = (n_x8 + 255) / 256;
    prep_kernel<<<96 + xblk, 256, 0, stream>>>(x, W1, W2, wsh, xh, n_x8);

    int nblk = (E + 127) / 128;
    edge_mlp_kernel<<<nblk, 256, 0, stream>>>(xh, ei, ew, W1, b1, b2, W3, b3,
                                              wsh, out, E);
}